// Round 3
// baseline (1334.297 us; speedup 1.0000x reference)
//
#include <hip/hip_runtime.h>
#include <hip/hip_bf16.h>

#define N_TASK 100000
#define N_DATA 50000
#define NE     1500000
// D_TASK = D_DATA = 64, D_EDGE = 16, H = 2, C = 64, H*C = 128
#define SCAN_B 1024
#define NB_SCAN 98   // ceil(100000/1024)

// ---- GEMV-style GEMM: Y[N,128] = X[N,64] @ W[64,128] + b ------------------
// one wave per row; x-row loaded once coalesced, broadcast via shfl
__global__ __launch_bounds__(256) void gemm_row(
    const float* __restrict__ X, const float* __restrict__ W,
    const float* __restrict__ b, float* __restrict__ Y, int N)
{
    int wave = (blockIdx.x * blockDim.x + threadIdx.x) >> 6;
    int lane = threadIdx.x & 63;
    if (wave >= N) return;
    float xv = X[(size_t)wave * 64 + lane];          // 1 coalesced load
    float2 acc = *(const float2*)(b + lane * 2);
#pragma unroll 16
    for (int k = 0; k < 64; ++k) {
        float xk = __shfl(xv, k);                    // VALU broadcast
        float2 w2 = *(const float2*)(W + k * 128 + lane * 2);  // L1-resident
        acc.x += xk * w2.x; acc.y += xk * w2.y;
    }
    *(float2*)(Y + (size_t)wave * 128 + lane * 2) = acc;
}

// ---- counting sort by dst --------------------------------------------------
__global__ __launch_bounds__(256) void zero_hist(int* __restrict__ hist)
{
    int i = blockIdx.x * blockDim.x + threadIdx.x;
    if (i < N_TASK) hist[i] = 0;
}

__global__ __launch_bounds__(256) void hist_k(
    const int* __restrict__ dst, int* __restrict__ hist)
{
    int e = blockIdx.x * blockDim.x + threadIdx.x;
    if (e < NE) atomicAdd(&hist[dst[e]], 1);
}

__global__ __launch_bounds__(SCAN_B) void scan_block(
    const int* __restrict__ hist, int* __restrict__ incl, int* __restrict__ bsums)
{
    __shared__ int s[SCAN_B];
    int tid = threadIdx.x;
    int i = blockIdx.x * SCAN_B + tid;
    int v = (i < N_TASK) ? hist[i] : 0;
    s[tid] = v;
    __syncthreads();
#pragma unroll
    for (int off = 1; off < SCAN_B; off <<= 1) {
        int t = (tid >= off) ? s[tid - off] : 0;
        __syncthreads();
        s[tid] += t;
        __syncthreads();
    }
    if (i < N_TASK) incl[i] = s[tid];
    if (tid == SCAN_B - 1) bsums[blockIdx.x] = s[tid];
}

__global__ __launch_bounds__(128) void scan_sums(
    const int* __restrict__ bsums, int* __restrict__ bbase)
{
    __shared__ int s[128];
    int tid = threadIdx.x;
    s[tid] = (tid < NB_SCAN) ? bsums[tid] : 0;
    __syncthreads();
#pragma unroll
    for (int off = 1; off < 128; off <<= 1) {
        int t = (tid >= off) ? s[tid - off] : 0;
        __syncthreads();
        s[tid] += t;
        __syncthreads();
    }
    int ex = (tid == 0) ? 0 : s[tid - 1];
    if (tid < NB_SCAN) bbase[tid] = ex;
}

__global__ __launch_bounds__(256) void finalize_scan(
    const int* __restrict__ incl, const int* __restrict__ hist,
    const int* __restrict__ bbase, int* __restrict__ start, int* __restrict__ cursor)
{
    int i = blockIdx.x * blockDim.x + threadIdx.x;
    if (i >= N_TASK) return;
    int st = incl[i] - hist[i] + bbase[i >> 10];
    start[i] = st;
    cursor[i] = st;
}

__global__ __launch_bounds__(256) void scatter_sort(
    const int* __restrict__ src, const int* __restrict__ dst,
    int* __restrict__ cursor, int2* __restrict__ sedge)
{
    int e = blockIdx.x * blockDim.x + threadIdx.x;
    if (e >= NE) return;
    int d = dst[e];
    int pos = atomicAdd(&cursor[d], 1);
    sedge[pos] = make_int2(src[e], e);
}

// ---- per-edge alpha precursor (everything before the cross-lane reduce) ----
__device__ __forceinline__ float prealpha(
    float2 xv, float2 xrv, float2 at, const float2* Wev,
    float4 q0, float4 q1, float4 q2, float4 q3)
{
    float ev0, ev1;
    ev0  = q0.x * Wev[0].x;  ev1  = q0.x * Wev[0].y;
    ev0 += q0.y * Wev[1].x;  ev1 += q0.y * Wev[1].y;
    ev0 += q0.z * Wev[2].x;  ev1 += q0.z * Wev[2].y;
    ev0 += q0.w * Wev[3].x;  ev1 += q0.w * Wev[3].y;
    ev0 += q1.x * Wev[4].x;  ev1 += q1.x * Wev[4].y;
    ev0 += q1.y * Wev[5].x;  ev1 += q1.y * Wev[5].y;
    ev0 += q1.z * Wev[6].x;  ev1 += q1.z * Wev[6].y;
    ev0 += q1.w * Wev[7].x;  ev1 += q1.w * Wev[7].y;
    ev0 += q2.x * Wev[8].x;  ev1 += q2.x * Wev[8].y;
    ev0 += q2.y * Wev[9].x;  ev1 += q2.y * Wev[9].y;
    ev0 += q2.z * Wev[10].x; ev1 += q2.z * Wev[10].y;
    ev0 += q2.w * Wev[11].x; ev1 += q2.w * Wev[11].y;
    ev0 += q3.x * Wev[12].x; ev1 += q3.x * Wev[12].y;
    ev0 += q3.y * Wev[13].x; ev1 += q3.y * Wev[13].y;
    ev0 += q3.z * Wev[14].x; ev1 += q3.z * Wev[14].y;
    ev0 += q3.w * Wev[15].x; ev1 += q3.w * Wev[15].y;
    float v0 = xv.x + xrv.x + ev0; v0 = v0 > 0.f ? v0 : 0.2f * v0;
    float v1 = xv.y + xrv.y + ev1; v1 = v1 > 0.f ? v1 : 0.2f * v1;
    return v0 * at.x + v1 * at.y;
}

// ---- fused GAT + softmax + residual + LayerNorm + concat -------------------
// one wave per task node; lane l: channels (2l,2l+1); lanes 0-31 head0, 32-63 head1
__global__ __launch_bounds__(256) void node_gat(
    const float* __restrict__ xl, const float* __restrict__ xr,
    const float* __restrict__ ea, const float* __restrict__ We,
    const float* __restrict__ att,
    const int* __restrict__ seg_start, const int* __restrict__ seg_cnt,
    const int2* __restrict__ sedge,
    const float* __restrict__ tx, const float* __restrict__ Wres,
    const float* __restrict__ bias, const float* __restrict__ g,
    const float* __restrict__ beta, float* __restrict__ out)
{
    __shared__ float Ws[64 * 64];
    for (int i = threadIdx.x; i < 64 * 64; i += 256) Ws[i] = Wres[i];
    __syncthreads();

    int wv = threadIdx.x >> 6;
    int lane = threadIdx.x & 63;
    int li = lane & 31;
    int n = blockIdx.x * 4 + wv;
    if (n >= N_TASK) return;

    float2 Wev[16];
#pragma unroll
    for (int k = 0; k < 16; ++k) Wev[k] = *(const float2*)(We + k * 128 + lane * 2);

    float2 xrv = *(const float2*)(xr + (size_t)n * 128 + lane * 2);
    float2 at  = *(const float2*)(att + lane * 2);

    int beg = __builtin_amdgcn_readfirstlane(seg_start[n]);
    int cnt = __builtin_amdgcn_readfirstlane(seg_cnt[n]);

    float acc0 = 0.f, acc1 = 0.f, den = 0.f;

    auto accum2 = [&](float pA, float pB, float2 ca, float2 cb) {
#pragma unroll
        for (int m = 1; m <= 16; m <<= 1) {
            pA += __shfl_xor(pA, m);
            pB += __shfl_xor(pB, m);
        }
        float wA = __expf(pA), wB = __expf(pB);
        den  += wA + wB;
        acc0 += wA * ca.x + wB * cb.x;
        acc1 += wA * ca.y + wB * cb.y;
    };
    auto accum1 = [&](float p, float2 c) {
#pragma unroll
        for (int m = 1; m <= 16; m <<= 1) p += __shfl_xor(p, m);
        float w = __expf(p);
        den += w; acc0 += w * c.x; acc1 += w * c.y;
    };

#define FETCH(idx, xv, q0, q1, q2, q3) do {                                  \
    int2 se_ = sedge[beg + (idx)];                                           \
    int s_ = __builtin_amdgcn_readfirstlane(se_.x);                          \
    int e_ = __builtin_amdgcn_readfirstlane(se_.y);                          \
    xv = *(const float2*)(xl + (size_t)s_ * 128 + lane * 2);                 \
    const float4* ep_ = (const float4*)(ea + (size_t)e_ * 16);               \
    q0 = ep_[0]; q1 = ep_[1]; q2 = ep_[2]; q3 = ep_[3];                      \
} while (0)

    // 4-slot software pipeline
    float2 x0, x1, x2, x3;
    float4 a00, a01, a02, a03, a10, a11, a12, a13;
    float4 a20, a21, a22, a23, a30, a31, a32, a33;
    if (cnt > 0) FETCH(0, x0, a00, a01, a02, a03);
    if (cnt > 1) FETCH(1, x1, a10, a11, a12, a13);
    if (cnt > 2) FETCH(2, x2, a20, a21, a22, a23);
    if (cnt > 3) FETCH(3, x3, a30, a31, a32, a33);

    int i = 0;
    for (; i + 4 <= cnt; i += 4) {
        float pA = prealpha(x0, xrv, at, Wev, a00, a01, a02, a03);
        float pB = prealpha(x1, xrv, at, Wev, a10, a11, a12, a13);
        float2 c0 = x0, c1 = x1;
        if (i + 4 < cnt) FETCH(i + 4, x0, a00, a01, a02, a03);
        if (i + 5 < cnt) FETCH(i + 5, x1, a10, a11, a12, a13);
        accum2(pA, pB, c0, c1);
        pA = prealpha(x2, xrv, at, Wev, a20, a21, a22, a23);
        pB = prealpha(x3, xrv, at, Wev, a30, a31, a32, a33);
        float2 c2 = x2, c3 = x3;
        if (i + 6 < cnt) FETCH(i + 6, x2, a20, a21, a22, a23);
        if (i + 7 < cnt) FETCH(i + 7, x3, a30, a31, a32, a33);
        accum2(pA, pB, c2, c3);
    }
    int r = cnt - i;   // 0..3, held in slots S0..S2
    if (r >= 2) {
        float pA = prealpha(x0, xrv, at, Wev, a00, a01, a02, a03);
        float pB = prealpha(x1, xrv, at, Wev, a10, a11, a12, a13);
        accum2(pA, pB, x0, x1);
    }
    if (r == 1) {
        float p = prealpha(x0, xrv, at, Wev, a00, a01, a02, a03);
        accum1(p, x0);
    } else if (r == 3) {
        float p = prealpha(x2, xrv, at, Wev, a20, a21, a22, a23);
        accum1(p, x2);
    }
#undef FETCH

    float inv = 1.f / (den + 1e-16f);        // cnt==0 -> acc=0 -> matches ref
    float o0 = acc0 * inv, o1 = acc1 * inv;

    // head mean across the two 32-lane halves
    float m0 = 0.5f * (o0 + __shfl_xor(o0, 32));
    float m1 = 0.5f * (o1 + __shfl_xor(o1, 32));

    // residual GEMV
    const float* txr = tx + (size_t)n * 64;
    float r0 = 0.f, r1 = 0.f;
#pragma unroll 8
    for (int k = 0; k < 64; ++k) {
        float t = txr[k];
        float2 w2 = *(const float2*)(Ws + k * 64 + li * 2);
        r0 += t * w2.x; r1 += t * w2.y;
    }
    float o0f = m0 + r0 + bias[li * 2];
    float o1f = m1 + r1 + bias[li * 2 + 1];

    // LayerNorm over 64 channels (2/lane across each 32-lane half)
    float sum = o0f + o1f, ssq = o0f * o0f + o1f * o1f;
#pragma unroll
    for (int m = 1; m <= 16; m <<= 1) {
        sum += __shfl_xor(sum, m);
        ssq += __shfl_xor(ssq, m);
    }
    float mu = sum * (1.f / 64.f);
    float var = ssq * (1.f / 64.f) - mu * mu;
    float is = rsqrtf(var + 1e-5f);
    float x0o = (o0f - mu) * is * g[li * 2]     + beta[li * 2];
    float x1o = (o1f - mu) * is * g[li * 2 + 1] + beta[li * 2 + 1];
    x0o = x0o > 0.f ? x0o : 0.01f * x0o;
    x1o = x1o > 0.f ? x1o : 0.01f * x1o;

    if (lane < 32) {
        float2 o = {x0o, x1o};
        *(float2*)(out + (size_t)n * 128 + li * 2) = o;
    } else {
        float2 t2 = *(const float2*)(txr + li * 2);
        *(float2*)(out + (size_t)n * 128 + 64 + li * 2) = t2;
    }
}

extern "C" void kernel_launch(void* const* d_in, const int* in_sizes, int n_in,
                              void* d_out, int out_size, void* d_ws, size_t ws_size,
                              hipStream_t stream)
{
    const float* task_x    = (const float*)d_in[0];
    const float* data_x    = (const float*)d_in[1];
    const float* edge_attr = (const float*)d_in[2];
    const int*   src_idx   = (const int*)d_in[3];
    const int*   dst_idx   = (const int*)d_in[4];
    const float* W_l       = (const float*)d_in[5];
    const float* b_l       = (const float*)d_in[6];
    const float* W_r       = (const float*)d_in[7];
    const float* b_r       = (const float*)d_in[8];
    const float* W_e       = (const float*)d_in[9];
    const float* att       = (const float*)d_in[10];
    const float* W_res     = (const float*)d_in[11];
    const float* conv_bias = (const float*)d_in[12];
    const float* ln_g      = (const float*)d_in[13];
    const float* ln_b      = (const float*)d_in[14];
    float* out = (float*)d_out;

    // workspace layout: ~91 MB
    float* xl     = (float*)d_ws;              // 6,400,000 f
    float* xr     = xl + 6400000;              // 12,800,000 f
    int*   hist   = (int*)(xr + 12800000);     // 100,000
    int*   incl   = hist + 100000;             // 100,000
    int*   bsums  = incl + 100000;             // 128
    int*   bbase  = bsums + 128;               // 128
    int*   start  = bbase + 128;               // 100,000
    int*   cursor = start + 100000;            // 100,000
    int2*  sedge  = (int2*)(cursor + 100000);  // 1,500,000 int2

    gemm_row     <<<12500, 256, 0, stream>>>(data_x, W_l, b_l, xl, N_DATA);
    gemm_row     <<<25000, 256, 0, stream>>>(task_x, W_r, b_r, xr, N_TASK);
    zero_hist    <<<391, 256, 0, stream>>>(hist);
    hist_k       <<<5860, 256, 0, stream>>>(dst_idx, hist);
    scan_block   <<<NB_SCAN, SCAN_B, 0, stream>>>(hist, incl, bsums);
    scan_sums    <<<1, 128, 0, stream>>>(bsums, bbase);
    finalize_scan<<<391, 256, 0, stream>>>(incl, hist, bbase, start, cursor);
    scatter_sort <<<5860, 256, 0, stream>>>(src_idx, dst_idx, cursor, sedge);
    node_gat     <<<25000, 256, 0, stream>>>(xl, xr, edge_attr, W_e, att,
                                             start, hist, sedge,
                                             task_x, W_res, conv_bias, ln_g, ln_b, out);
}

// Round 4
// 726.200 us; speedup vs baseline: 1.8374x; 1.8374x over previous
//
#include <hip/hip_runtime.h>
#include <hip/hip_bf16.h>

#define N_TASK 100000
#define N_DATA 50000
#define NE     1500000
// D_TASK = D_DATA = 64, D_EDGE = 16, H = 2, C = 64, H*C = 128
#define SCAN_B 1024
#define NB_SCAN 98   // ceil(100000/1024)

// pack two floats as bf16 pair (RNE): low half = a, high half = b
__device__ __forceinline__ unsigned pack_bf16(float a, float b) {
    unsigned ua = __float_as_uint(a), ub = __float_as_uint(b);
    ua = (ua + 0x7fffu + ((ua >> 16) & 1u)) >> 16;
    ub = (ub + 0x7fffu + ((ub >> 16) & 1u)) & 0xffff0000u;
    return ua | ub;
}
// decode: x = low half, y = high half
__device__ __forceinline__ float bf_lo(unsigned u) { return __uint_as_float(u << 16); }
__device__ __forceinline__ float bf_hi(unsigned u) { return __uint_as_float(u & 0xffff0000u); }

// ---- fused prologue: gemm x_l (bf16 out), gemm x_r (f32 out), zero hist ----
// blocks [0,12500): x_l rows; [12500,37500): x_r rows; rest: zero hist+flags
__global__ __launch_bounds__(256) void fused_pre(
    const float* __restrict__ data_x, const float* __restrict__ Wl,
    const float* __restrict__ bl,
    const float* __restrict__ task_x, const float* __restrict__ Wr,
    const float* __restrict__ br,
    unsigned* __restrict__ xlb, float* __restrict__ xr,
    int* __restrict__ hist, unsigned long long* __restrict__ flags)
{
    int b = blockIdx.x;
    int lane = threadIdx.x & 63;
    if (b < 12500) {
        int row = b * 4 + (threadIdx.x >> 6);
        float xv = data_x[(size_t)row * 64 + lane];
        float2 acc = *(const float2*)(bl + lane * 2);
#pragma unroll 16
        for (int k = 0; k < 64; ++k) {
            float xk = __shfl(xv, k);
            float2 w2 = *(const float2*)(Wl + k * 128 + lane * 2);
            acc.x += xk * w2.x; acc.y += xk * w2.y;
        }
        xlb[(size_t)row * 64 + lane] = pack_bf16(acc.x, acc.y);
    } else if (b < 37500) {
        int row = (b - 12500) * 4 + (threadIdx.x >> 6);
        float xv = task_x[(size_t)row * 64 + lane];
        float2 acc = *(const float2*)(br + lane * 2);
#pragma unroll 16
        for (int k = 0; k < 64; ++k) {
            float xk = __shfl(xv, k);
            float2 w2 = *(const float2*)(Wr + k * 128 + lane * 2);
            acc.x += xk * w2.x; acc.y += xk * w2.y;
        }
        *(float2*)(xr + (size_t)row * 128 + lane * 2) = acc;
    } else {
        int i = (b - 37500) * 256 + threadIdx.x;
        if (i < N_TASK) hist[i] = 0;
        if (i < NB_SCAN) flags[i] = 0ULL;
    }
}

__global__ __launch_bounds__(256) void hist_k(
    const int* __restrict__ dst, int* __restrict__ hist)
{
    int e = blockIdx.x * blockDim.x + threadIdx.x;
    if (e < NE) atomicAdd(&hist[dst[e]], 1);
}

// ---- single-kernel decoupled-lookback exclusive scan -----------------------
// flags[b]: (state<<32)|value; state 1 = aggregate, 2 = inclusive prefix
__global__ __launch_bounds__(SCAN_B) void scan_lookback(
    const int* __restrict__ hist, unsigned long long* __restrict__ flags,
    int* __restrict__ start, int* __restrict__ cursor)
{
    __shared__ int s[SCAN_B];
    __shared__ int ex_sh;
    int tid = threadIdx.x, b = blockIdx.x;
    int i = b * SCAN_B + tid;
    int v = (i < N_TASK) ? hist[i] : 0;
    s[tid] = v;
    __syncthreads();
#pragma unroll
    for (int off = 1; off < SCAN_B; off <<= 1) {
        int t = (tid >= off) ? s[tid - off] : 0;
        __syncthreads();
        s[tid] += t;
        __syncthreads();
    }
    int incl = s[tid];
    if (tid == 0) {
        int total = s[SCAN_B - 1];
        __hip_atomic_store(&flags[b], (1ULL << 32) | (unsigned)total,
                           __ATOMIC_RELEASE, __HIP_MEMORY_SCOPE_AGENT);
        int ex = 0;
        for (int p = b - 1; p >= 0; --p) {
            unsigned long long f;
            do {
                f = __hip_atomic_load(&flags[p], __ATOMIC_ACQUIRE,
                                      __HIP_MEMORY_SCOPE_AGENT);
            } while ((f >> 32) == 0ULL);
            ex += (int)(unsigned)f;
            if ((f >> 32) == 2ULL) break;
        }
        __hip_atomic_store(&flags[b], (2ULL << 32) | (unsigned)(ex + total),
                           __ATOMIC_RELEASE, __HIP_MEMORY_SCOPE_AGENT);
        ex_sh = ex;
    }
    __syncthreads();
    if (i < N_TASK) {
        int st = ex_sh + incl - v;
        start[i] = st;
        cursor[i] = st;
    }
}

// ---- sort scatter: src index + edge_attr (as bf16) into dst-sorted order ---
__global__ __launch_bounds__(256) void scatter_sort(
    const int* __restrict__ src, const int* __restrict__ dst,
    const float* __restrict__ ea, int* __restrict__ cursor,
    int* __restrict__ ssrc, uint4* __restrict__ sea)
{
    int e = blockIdx.x * blockDim.x + threadIdx.x;
    if (e >= NE) return;
    int d = dst[e];
    int pos = atomicAdd(&cursor[d], 1);
    ssrc[pos] = src[e];
    const float4* p = (const float4*)(ea + (size_t)e * 16);
    float4 q0 = p[0], q1 = p[1], q2 = p[2], q3 = p[3];
    uint4 o0, o1;
    o0.x = pack_bf16(q0.x, q0.y); o0.y = pack_bf16(q0.z, q0.w);
    o0.z = pack_bf16(q1.x, q1.y); o0.w = pack_bf16(q1.z, q1.w);
    o1.x = pack_bf16(q2.x, q2.y); o1.y = pack_bf16(q2.z, q2.w);
    o1.z = pack_bf16(q3.x, q3.y); o1.w = pack_bf16(q3.z, q3.w);
    sea[(size_t)pos * 2]     = o0;
    sea[(size_t)pos * 2 + 1] = o1;
}

// ---- fused GAT + softmax + residual + LayerNorm + concat -------------------
// one wave per task node; lane l: channels (2l,2l+1); lanes 0-31 head0, 32-63 head1
__global__ __launch_bounds__(256) void node_gat(
    const unsigned* __restrict__ xlb, const float* __restrict__ xr,
    const uint4* __restrict__ sea, const float* __restrict__ We,
    const float* __restrict__ att,
    const int* __restrict__ seg_start, const int* __restrict__ seg_cnt,
    const int* __restrict__ ssrc,
    const float* __restrict__ tx, const float* __restrict__ Wres,
    const float* __restrict__ bias, const float* __restrict__ g,
    const float* __restrict__ beta, float* __restrict__ out)
{
    __shared__ float Ws[64 * 64];
    for (int i = threadIdx.x; i < 64 * 64; i += 256) Ws[i] = Wres[i];
    __syncthreads();

    int wv = threadIdx.x >> 6;
    int lane = threadIdx.x & 63;
    int li = lane & 31;
    int n = blockIdx.x * 4 + wv;
    if (n >= N_TASK) return;

    float2 Wev[16];
#pragma unroll
    for (int k = 0; k < 16; ++k) Wev[k] = *(const float2*)(We + k * 128 + lane * 2);

    float2 xrv = *(const float2*)(xr + (size_t)n * 128 + lane * 2);
    float2 at  = *(const float2*)(att + lane * 2);

    int beg = __builtin_amdgcn_readfirstlane(seg_start[n]);
    int cnt = __builtin_amdgcn_readfirstlane(seg_cnt[n]);

    float acc0 = 0.f, acc1 = 0.f, den = 0.f;

    // depth-1 software pipeline (round-2 schedule, lighter payload)
    unsigned xu_p = 0;
    uint4 e0_p = {0,0,0,0}, e1_p = {0,0,0,0};
    if (cnt > 0) {
        int s0 = __builtin_amdgcn_readfirstlane(ssrc[beg]);
        xu_p = xlb[(size_t)s0 * 64 + lane];
        e0_p = sea[(size_t)beg * 2];
        e1_p = sea[(size_t)beg * 2 + 1];
    }
    for (int i = 0; i < cnt; ++i) {
        unsigned xu = xu_p;
        uint4 u0 = e0_p, u1 = e1_p;
        if (i + 1 < cnt) {
            int s1 = __builtin_amdgcn_readfirstlane(ssrc[beg + i + 1]);
            xu_p = xlb[(size_t)s1 * 64 + lane];
            e0_p = sea[(size_t)(beg + i + 1) * 2];
            e1_p = sea[(size_t)(beg + i + 1) * 2 + 1];
        }
        float c[16] = {bf_lo(u0.x), bf_hi(u0.x), bf_lo(u0.y), bf_hi(u0.y),
                       bf_lo(u0.z), bf_hi(u0.z), bf_lo(u0.w), bf_hi(u0.w),
                       bf_lo(u1.x), bf_hi(u1.x), bf_lo(u1.y), bf_hi(u1.y),
                       bf_lo(u1.z), bf_hi(u1.z), bf_lo(u1.w), bf_hi(u1.w)};
        float ev0 = 0.f, ev1 = 0.f;
#pragma unroll
        for (int k = 0; k < 16; ++k) { ev0 += c[k] * Wev[k].x; ev1 += c[k] * Wev[k].y; }
        float xlx = bf_lo(xu), xly = bf_hi(xu);
        float v0 = xlx + xrv.x + ev0; v0 = v0 > 0.f ? v0 : 0.2f * v0;
        float v1 = xly + xrv.y + ev1; v1 = v1 > 0.f ? v1 : 0.2f * v1;
        float p = v0 * at.x + v1 * at.y;
#pragma unroll
        for (int m = 1; m <= 16; m <<= 1) p += __shfl_xor(p, m);  // per-head alpha
        // |alpha| is small (~<5): exp without max subtraction is exact enough
        float w = __expf(p);
        den += w;
        acc0 += w * xlx;
        acc1 += w * xly;
    }

    float inv = 1.f / (den + 1e-16f);        // cnt==0 -> acc=0 -> matches ref
    float o0 = acc0 * inv, o1 = acc1 * inv;

    // head mean across the two 32-lane halves
    float m0 = 0.5f * (o0 + __shfl_xor(o0, 32));
    float m1 = 0.5f * (o1 + __shfl_xor(o1, 32));

    // residual GEMV
    const float* txr = tx + (size_t)n * 64;
    float r0 = 0.f, r1 = 0.f;
#pragma unroll 8
    for (int k = 0; k < 64; ++k) {
        float t = txr[k];
        float2 w2 = *(const float2*)(Ws + k * 64 + li * 2);
        r0 += t * w2.x; r1 += t * w2.y;
    }
    float o0f = m0 + r0 + bias[li * 2];
    float o1f = m1 + r1 + bias[li * 2 + 1];

    // LayerNorm over 64 channels (2/lane across each 32-lane half)
    float sum = o0f + o1f, ssq = o0f * o0f + o1f * o1f;
#pragma unroll
    for (int m = 1; m <= 16; m <<= 1) {
        sum += __shfl_xor(sum, m);
        ssq += __shfl_xor(ssq, m);
    }
    float mu = sum * (1.f / 64.f);
    float var = ssq * (1.f / 64.f) - mu * mu;
    float is = rsqrtf(var + 1e-5f);
    float x0o = (o0f - mu) * is * g[li * 2]     + beta[li * 2];
    float x1o = (o1f - mu) * is * g[li * 2 + 1] + beta[li * 2 + 1];
    x0o = x0o > 0.f ? x0o : 0.01f * x0o;
    x1o = x1o > 0.f ? x1o : 0.01f * x1o;

    if (lane < 32) {
        float2 o = {x0o, x1o};
        *(float2*)(out + (size_t)n * 128 + li * 2) = o;
    } else {
        float2 t2 = *(const float2*)(txr + li * 2);
        *(float2*)(out + (size_t)n * 128 + 64 + li * 2) = t2;
    }
}

extern "C" void kernel_launch(void* const* d_in, const int* in_sizes, int n_in,
                              void* d_out, int out_size, void* d_ws, size_t ws_size,
                              hipStream_t stream)
{
    const float* task_x    = (const float*)d_in[0];
    const float* data_x    = (const float*)d_in[1];
    const float* edge_attr = (const float*)d_in[2];
    const int*   src_idx   = (const int*)d_in[3];
    const int*   dst_idx   = (const int*)d_in[4];
    const float* W_l       = (const float*)d_in[5];
    const float* b_l       = (const float*)d_in[6];
    const float* W_r       = (const float*)d_in[7];
    const float* b_r       = (const float*)d_in[8];
    const float* W_e       = (const float*)d_in[9];
    const float* att       = (const float*)d_in[10];
    const float* W_res     = (const float*)d_in[11];
    const float* conv_bias = (const float*)d_in[12];
    const float* ln_g      = (const float*)d_in[13];
    const float* ln_b      = (const float*)d_in[14];
    float* out = (float*)d_out;

    // workspace layout (~120 MB)
    unsigned* xlb  = (unsigned*)d_ws;                    // 3,200,000 u32 (x_l bf16)
    float*    xr   = (float*)(xlb + 3200000);            // 12,800,000 f
    int*      hist = (int*)(xr + 12800000);              // 100,000
    int*     start = hist + 100000;                      // 100,000
    int*    cursor = start + 100000;                     // 100,000
    unsigned long long* flags = (unsigned long long*)(cursor + 100000); // 128
    int*      ssrc = (int*)(flags + 128);                // 1,500,000
    uint4*    sea  = (uint4*)(ssrc + 1500000 + 4);       // 1,500,000 uint4x2 (48MB)

    fused_pre   <<<37891, 256, 0, stream>>>(data_x, W_l, b_l, task_x, W_r, b_r,
                                            xlb, xr, hist, flags);
    hist_k      <<<5860, 256, 0, stream>>>(dst_idx, hist);
    scan_lookback<<<NB_SCAN, SCAN_B, 0, stream>>>(hist, flags, start, cursor);
    scatter_sort<<<5860, 256, 0, stream>>>(src_idx, dst_idx, edge_attr, cursor,
                                           ssrc, sea);
    node_gat    <<<25000, 256, 0, stream>>>(xlb, xr, sea, W_e, att,
                                            start, hist, ssrc,
                                            task_x, W_res, conv_bias, ln_g, ln_b, out);
}

// Round 5
// 695.705 us; speedup vs baseline: 1.9179x; 1.0438x over previous
//
#include <hip/hip_runtime.h>
#include <hip/hip_bf16.h>

#define N_TASK 100000
#define N_DATA 50000
#define NE     1500000
// D_TASK = D_DATA = 64, D_EDGE = 16, H = 2, C = 64, H*C = 128
#define SCAN_B 1024
#define NB_SCAN 98   // ceil(100000/1024)

typedef _Float16 half2v __attribute__((ext_vector_type(2)));

__device__ __forceinline__ unsigned pack_f16(float a, float b) {
    half2v h = {(_Float16)a, (_Float16)b};
    return __builtin_bit_cast(unsigned, h);
}
__device__ __forceinline__ float f16_lo(unsigned u) {
    half2v h = __builtin_bit_cast(half2v, u); return (float)h.x;
}
__device__ __forceinline__ float f16_hi(unsigned u) {
    half2v h = __builtin_bit_cast(half2v, u); return (float)h.y;
}
// f32 += f16x2 . f16x2 (v_dot2_f32_f16), with scalar fallback
__device__ __forceinline__ float fdot2f(unsigned a, unsigned b, float c) {
#if __has_builtin(__builtin_amdgcn_fdot2)
    return __builtin_amdgcn_fdot2(__builtin_bit_cast(half2v, a),
                                  __builtin_bit_cast(half2v, b), c, false);
#else
    return c + f16_lo(a) * f16_lo(b) + f16_hi(a) * f16_hi(b);
#endif
}

// ---- fused prologue ---------------------------------------------------------
// blocks [0,12500):      x_l rows (f16-pair out)
// blocks [12500,37500):  x_r rows (f16-pair out)
// blocks [37500,43360):  dst histogram (hist pre-zeroed by memsetAsync)
// blocks [43360,49220):  edge_attr -> f16 pairs (in edge order)
// block  49220:          pack W_e into k-pair f16 layout Wp[kp*128+col]
__global__ __launch_bounds__(256) void fused_pre(
    const float* __restrict__ data_x, const float* __restrict__ Wl,
    const float* __restrict__ bl,
    const float* __restrict__ task_x, const float* __restrict__ Wr,
    const float* __restrict__ br,
    const float* __restrict__ ea, const int* __restrict__ dst,
    const float* __restrict__ We,
    unsigned* __restrict__ xlb, unsigned* __restrict__ xrb,
    uint4* __restrict__ eaf, unsigned* __restrict__ Wp,
    int* __restrict__ hist)
{
    int b = blockIdx.x;
    int lane = threadIdx.x & 63;
    if (b < 12500) {
        int row = b * 4 + (threadIdx.x >> 6);
        float xv = data_x[(size_t)row * 64 + lane];
        float2 acc = *(const float2*)(bl + lane * 2);
#pragma unroll 16
        for (int k = 0; k < 64; ++k) {
            float xk = __shfl(xv, k);
            float2 w2 = *(const float2*)(Wl + k * 128 + lane * 2);
            acc.x += xk * w2.x; acc.y += xk * w2.y;
        }
        xlb[(size_t)row * 64 + lane] = pack_f16(acc.x, acc.y);
    } else if (b < 37500) {
        int row = (b - 12500) * 4 + (threadIdx.x >> 6);
        float xv = task_x[(size_t)row * 64 + lane];
        float2 acc = *(const float2*)(br + lane * 2);
#pragma unroll 16
        for (int k = 0; k < 64; ++k) {
            float xk = __shfl(xv, k);
            float2 w2 = *(const float2*)(Wr + k * 128 + lane * 2);
            acc.x += xk * w2.x; acc.y += xk * w2.y;
        }
        xrb[(size_t)row * 64 + lane] = pack_f16(acc.x, acc.y);
    } else if (b < 43360) {
        int e = (b - 37500) * 256 + threadIdx.x;
        if (e < NE) atomicAdd(&hist[dst[e]], 1);
    } else if (b < 49220) {
        int e = (b - 43360) * 256 + threadIdx.x;
        if (e < NE) {
            const float4* p = (const float4*)(ea + (size_t)e * 16);
            float4 q0 = p[0], q1 = p[1], q2 = p[2], q3 = p[3];
            uint4 o0, o1;
            o0.x = pack_f16(q0.x, q0.y); o0.y = pack_f16(q0.z, q0.w);
            o0.z = pack_f16(q1.x, q1.y); o0.w = pack_f16(q1.z, q1.w);
            o1.x = pack_f16(q2.x, q2.y); o1.y = pack_f16(q2.z, q2.w);
            o1.z = pack_f16(q3.x, q3.y); o1.w = pack_f16(q3.z, q3.w);
            eaf[(size_t)e * 2]     = o0;
            eaf[(size_t)e * 2 + 1] = o1;
        }
    } else {
#pragma unroll
        for (int r = 0; r < 4; ++r) {
            int idx = threadIdx.x * 4 + r;          // kp*128 + col
            int kp = idx >> 7, col = idx & 127;
            Wp[idx] = pack_f16(We[(2 * kp) * 128 + col],
                               We[(2 * kp + 1) * 128 + col]);
        }
    }
}

// ---- single-kernel decoupled-lookback exclusive scan -----------------------
__global__ __launch_bounds__(SCAN_B) void scan_lookback(
    const int* __restrict__ hist, unsigned long long* __restrict__ flags,
    int* __restrict__ start, int* __restrict__ cursor)
{
    __shared__ int s[SCAN_B];
    __shared__ int ex_sh;
    int tid = threadIdx.x, b = blockIdx.x;
    int i = b * SCAN_B + tid;
    int v = (i < N_TASK) ? hist[i] : 0;
    s[tid] = v;
    __syncthreads();
#pragma unroll
    for (int off = 1; off < SCAN_B; off <<= 1) {
        int t = (tid >= off) ? s[tid - off] : 0;
        __syncthreads();
        s[tid] += t;
        __syncthreads();
    }
    int incl = s[tid];
    if (tid == 0) {
        int total = s[SCAN_B - 1];
        __hip_atomic_store(&flags[b], (1ULL << 32) | (unsigned)total,
                           __ATOMIC_RELEASE, __HIP_MEMORY_SCOPE_AGENT);
        int ex = 0;
        for (int p = b - 1; p >= 0; --p) {
            unsigned long long f;
            do {
                f = __hip_atomic_load(&flags[p], __ATOMIC_ACQUIRE,
                                      __HIP_MEMORY_SCOPE_AGENT);
            } while ((f >> 32) == 0ULL);
            ex += (int)(unsigned)f;
            if ((f >> 32) == 2ULL) break;
        }
        __hip_atomic_store(&flags[b], (2ULL << 32) | (unsigned)(ex + total),
                           __ATOMIC_RELEASE, __HIP_MEMORY_SCOPE_AGENT);
        ex_sh = ex;
    }
    __syncthreads();
    if (i < N_TASK) {
        int st = ex_sh + incl - v;
        start[i] = st;
        cursor[i] = st;
    }
}

// ---- sort scatter: (src, eid) into dst-sorted order (8 B random writes) ----
__global__ __launch_bounds__(256) void scatter_sort(
    const int* __restrict__ src, const int* __restrict__ dst,
    int* __restrict__ cursor, int2* __restrict__ sedge)
{
    int e = blockIdx.x * blockDim.x + threadIdx.x;
    if (e >= NE) return;
    int d = dst[e];
    int pos = atomicAdd(&cursor[d], 1);
    sedge[pos] = make_int2(src[e], e);
}

// ---- fused GAT + softmax + residual + LayerNorm + concat -------------------
// one wave per task node; lane l: channels (2l,2l+1) i.e. cols 2l,2l+1 of [H*C]
__global__ __launch_bounds__(256) void node_gat(
    const unsigned* __restrict__ xlb, const unsigned* __restrict__ xrb,
    const uint4* __restrict__ eaf, const unsigned* __restrict__ Wp,
    const float* __restrict__ att,
    const int* __restrict__ seg_start, const int* __restrict__ seg_cnt,
    const int2* __restrict__ sedge,
    const float* __restrict__ tx, const float* __restrict__ Wres,
    const float* __restrict__ bias, const float* __restrict__ g,
    const float* __restrict__ beta, float* __restrict__ out)
{
    __shared__ float Ws[64 * 64];
    for (int i = threadIdx.x; i < 64 * 64; i += 256) Ws[i] = Wres[i];
    __syncthreads();

    int wv = threadIdx.x >> 6;
    int lane = threadIdx.x & 63;
    int li = lane & 31;
    int n = blockIdx.x * 4 + wv;
    if (n >= N_TASK) return;

    // W_e k-pair fragments for this lane's two columns
    const uint2* Wp2 = (const uint2*)Wp;
    uint2 wp0 = Wp2[0 * 64 + lane], wp1 = Wp2[1 * 64 + lane];
    uint2 wp2 = Wp2[2 * 64 + lane], wp3 = Wp2[3 * 64 + lane];
    uint2 wp4 = Wp2[4 * 64 + lane], wp5 = Wp2[5 * 64 + lane];
    uint2 wp6 = Wp2[6 * 64 + lane], wp7 = Wp2[7 * 64 + lane];

    unsigned xru = xrb[(size_t)n * 64 + lane];
    float xr0 = f16_lo(xru), xr1 = f16_hi(xru);
    float2 at = *(const float2*)(att + lane * 2);

    int beg = __builtin_amdgcn_readfirstlane(seg_start[n]);
    int cnt = __builtin_amdgcn_readfirstlane(seg_cnt[n]);

    float acc0 = 0.f, acc1 = 0.f, den = 0.f;

    // pre-lrelu-dot for one edge; also returns decoded x_l pair
    auto palpha = [&](unsigned xu, uint4 u0, uint4 u1, float& xx, float& xy) {
        float ev0 = 0.f, ev1 = 0.f;
        ev0 = fdot2f(u0.x, wp0.x, ev0); ev1 = fdot2f(u0.x, wp0.y, ev1);
        ev0 = fdot2f(u0.y, wp1.x, ev0); ev1 = fdot2f(u0.y, wp1.y, ev1);
        ev0 = fdot2f(u0.z, wp2.x, ev0); ev1 = fdot2f(u0.z, wp2.y, ev1);
        ev0 = fdot2f(u0.w, wp3.x, ev0); ev1 = fdot2f(u0.w, wp3.y, ev1);
        ev0 = fdot2f(u1.x, wp4.x, ev0); ev1 = fdot2f(u1.x, wp4.y, ev1);
        ev0 = fdot2f(u1.y, wp5.x, ev0); ev1 = fdot2f(u1.y, wp5.y, ev1);
        ev0 = fdot2f(u1.z, wp6.x, ev0); ev1 = fdot2f(u1.z, wp6.y, ev1);
        ev0 = fdot2f(u1.w, wp7.x, ev0); ev1 = fdot2f(u1.w, wp7.y, ev1);
        xx = f16_lo(xu); xy = f16_hi(xu);
        float v0 = xx + xr0 + ev0; v0 = v0 > 0.f ? v0 : 0.2f * v0;
        float v1 = xy + xr1 + ev1; v1 = v1 > 0.f ? v1 : 0.2f * v1;
        return v0 * at.x + v1 * at.y;
    };

#define PAYLOAD(se, xu, e0, e1) do {                                         \
    int s_ = __builtin_amdgcn_readfirstlane((se).x);                         \
    int e_ = __builtin_amdgcn_readfirstlane((se).y);                         \
    xu = xlb[(size_t)s_ * 64 + lane];                                        \
    const uint4* p_ = eaf + (size_t)e_ * 2;                                  \
    e0 = p_[0]; e1 = p_[1];                                                  \
} while (0)

    // depth-2 payload slots + depth-4 index prefetch
    int2 se0 = {0, 0}, se1 = {0, 0};
    unsigned xuA = 0, xuB = 0;
    uint4 A0 = {0,0,0,0}, A1 = {0,0,0,0}, B0 = {0,0,0,0}, B1 = {0,0,0,0};
    if (cnt > 0) se0 = sedge[beg];
    if (cnt > 1) se1 = sedge[beg + 1];
    if (cnt > 0) PAYLOAD(se0, xuA, A0, A1);
    if (cnt > 1) PAYLOAD(se1, xuB, B0, B1);
    if (cnt > 2) se0 = sedge[beg + 2];
    if (cnt > 3) se1 = sedge[beg + 3];

    int i = 0;
    for (; i + 2 <= cnt; i += 2) {
        float xax, xay, xbx, xby;
        float pA = palpha(xuA, A0, A1, xax, xay);
        float pB = palpha(xuB, B0, B1, xbx, xby);
        if (i + 2 < cnt) PAYLOAD(se0, xuA, A0, A1);
        if (i + 3 < cnt) PAYLOAD(se1, xuB, B0, B1);
        if (i + 4 < cnt) se0 = sedge[beg + i + 4];
        if (i + 5 < cnt) se1 = sedge[beg + i + 5];
#pragma unroll
        for (int m = 1; m <= 16; m <<= 1) {
            pA += __shfl_xor(pA, m);
            pB += __shfl_xor(pB, m);
        }
        float wA = __expf(pA), wB = __expf(pB);
        den  += wA + wB;
        acc0 += wA * xax + wB * xbx;
        acc1 += wA * xay + wB * xby;
    }
    if (i < cnt) {   // odd leftover sits in slot A
        float xax, xay;
        float p = palpha(xuA, A0, A1, xax, xay);
#pragma unroll
        for (int m = 1; m <= 16; m <<= 1) p += __shfl_xor(p, m);
        float w = __expf(p);
        den += w; acc0 += w * xax; acc1 += w * xay;
    }
#undef PAYLOAD

    float inv = 1.f / (den + 1e-16f);        // cnt==0 -> acc=0 -> matches ref
    float o0 = acc0 * inv, o1 = acc1 * inv;

    // head mean across the two 32-lane halves
    float m0 = 0.5f * (o0 + __shfl_xor(o0, 32));
    float m1 = 0.5f * (o1 + __shfl_xor(o1, 32));

    // residual GEMV
    const float* txr = tx + (size_t)n * 64;
    float r0 = 0.f, r1 = 0.f;
#pragma unroll 8
    for (int k = 0; k < 64; ++k) {
        float t = txr[k];
        float2 w2 = *(const float2*)(Ws + k * 64 + li * 2);
        r0 += t * w2.x; r1 += t * w2.y;
    }
    float o0f = m0 + r0 + bias[li * 2];
    float o1f = m1 + r1 + bias[li * 2 + 1];

    // LayerNorm over 64 channels (2/lane across each 32-lane half)
    float sum = o0f + o1f, ssq = o0f * o0f + o1f * o1f;
#pragma unroll
    for (int m = 1; m <= 16; m <<= 1) {
        sum += __shfl_xor(sum, m);
        ssq += __shfl_xor(ssq, m);
    }
    float mu = sum * (1.f / 64.f);
    float var = ssq * (1.f / 64.f) - mu * mu;
    float is = rsqrtf(var + 1e-5f);
    float x0o = (o0f - mu) * is * g[li * 2]     + beta[li * 2];
    float x1o = (o1f - mu) * is * g[li * 2 + 1] + beta[li * 2 + 1];
    x0o = x0o > 0.f ? x0o : 0.01f * x0o;
    x1o = x1o > 0.f ? x1o : 0.01f * x1o;

    if (lane < 32) {
        float2 o = {x0o, x1o};
        *(float2*)(out + (size_t)n * 128 + li * 2) = o;
    } else {
        float2 t2 = *(const float2*)(txr + li * 2);
        *(float2*)(out + (size_t)n * 128 + 64 + li * 2) = t2;
    }
}

extern "C" void kernel_launch(void* const* d_in, const int* in_sizes, int n_in,
                              void* d_out, int out_size, void* d_ws, size_t ws_size,
                              hipStream_t stream)
{
    const float* task_x    = (const float*)d_in[0];
    const float* data_x    = (const float*)d_in[1];
    const float* edge_attr = (const float*)d_in[2];
    const int*   src_idx   = (const int*)d_in[3];
    const int*   dst_idx   = (const int*)d_in[4];
    const float* W_l       = (const float*)d_in[5];
    const float* b_l       = (const float*)d_in[6];
    const float* W_r       = (const float*)d_in[7];
    const float* b_r       = (const float*)d_in[8];
    const float* W_e       = (const float*)d_in[9];
    const float* att       = (const float*)d_in[10];
    const float* W_res     = (const float*)d_in[11];
    const float* conv_bias = (const float*)d_in[12];
    const float* ln_g      = (const float*)d_in[13];
    const float* ln_b      = (const float*)d_in[14];
    float* out = (float*)d_out;

    // workspace layout (~99.7 MB)
    unsigned* xlb  = (unsigned*)d_ws;                  // 3,200,000 u32 (x_l f16)
    unsigned* xrb  = xlb + 3200000;                    // 6,400,000 u32 (x_r f16)
    uint4*    eaf  = (uint4*)(xrb + 6400000);          // 3,000,000 uint4 (ea f16)
    unsigned* Wp   = (unsigned*)(eaf + 3000000);       // 1,024 (W_e k-pairs)
    int*      hist = (int*)(Wp + 1024);                // 100,000
    unsigned long long* flags = (unsigned long long*)(hist + 100000); // 128
    int*     start = (int*)(flags + 128);              // 100,000
    int*    cursor = start + 100000;                   // 100,000
    int2*    sedge = (int2*)(cursor + 100000);         // 1,500,000 int2

    // zero hist + flags (stream-ordered, graph-capturable)
    hipMemsetAsync(hist, 0, 100000 * sizeof(int) + 128 * sizeof(unsigned long long),
                   stream);
    fused_pre    <<<49221, 256, 0, stream>>>(data_x, W_l, b_l, task_x, W_r, b_r,
                                             edge_attr, dst_idx, W_e,
                                             xlb, xrb, eaf, Wp, hist);
    scan_lookback<<<NB_SCAN, SCAN_B, 0, stream>>>(hist, flags, start, cursor);
    scatter_sort <<<5860, 256, 0, stream>>>(src_idx, dst_idx, cursor, sedge);
    node_gat     <<<25000, 256, 0, stream>>>(xlb, xrb, eaf, Wp, att,
                                             start, hist, sedge,
                                             task_x, W_res, conv_bias, ln_g, ln_b, out);
}